// Round 4
// baseline (387.216 us; speedup 1.0000x reference)
//
#include <hip/hip_runtime.h>

// ---------------------------------------------------------------------------
// Two-layer GCN on MI355X.  Round 13: lean atomic prep + R10 gathers.
//   R11/R12 post-mortem: deeper per-wave pipelines regressed twice ->
//   gg reverted VERBATIM to the R10 2-node depth-1 form (70us, ~6TB/s
//   delivered gather traffic, near pattern limit).
//   Prep chain rewritten: histmat/scanB/a2/bucketB (csrTmp 32MB roundtrip,
//   92KB-LDS kernel at 196 blocks) -> 3 light kernels with global atomics:
//     1. memset  : degfx = 0
//     2. prepcnt : W-pack + per-edge 64b atomicAdd {deg,sum(ew<<24)} by dst
//     3. scanN   : per-bucket 512-scan -> dinv, nodeinfo, cur=0
//     4. gemm1   : h1s = dinv*(x@W1)  (MFMA, row-scaled epilogue)
//     5. scatter : p=atomicAdd(cur[dst]); csrF[base+p]={src,ew}
//     6. gg      : gather(ew) + bias/relu + MFMA gemm2, h2s = dinv*h2
//     7. gather64: gather(ew) + final scale + bias -> out fp32
// ---------------------------------------------------------------------------

#define N_NODES 100000
#define NBUCK   196
#define BSHIFT  9
#define BNODES  512
#define CAP     10240

typedef __attribute__((ext_vector_type(8))) short bf16x8;
typedef __attribute__((ext_vector_type(4))) float f32x4;

__device__ __forceinline__ unsigned bf16r(float f) {
    unsigned u = __float_as_uint(f);
    return (u + 0x7fffu + ((u >> 16) & 1u)) >> 16;     // RNE
}
__device__ __forceinline__ float bf_lo(unsigned u) { return __uint_as_float(u << 16); }
__device__ __forceinline__ float bf_hi(unsigned u) { return __uint_as_float(u & 0xffff0000u); }

__device__ __forceinline__ void fma8(float* a, uint4 u, float w) {
    a[0] = fmaf(bf_lo(u.x), w, a[0]); a[1] = fmaf(bf_hi(u.x), w, a[1]);
    a[2] = fmaf(bf_lo(u.y), w, a[2]); a[3] = fmaf(bf_hi(u.y), w, a[3]);
    a[4] = fmaf(bf_lo(u.z), w, a[4]); a[5] = fmaf(bf_hi(u.z), w, a[5]);
    a[6] = fmaf(bf_lo(u.w), w, a[6]); a[7] = fmaf(bf_hi(u.w), w, a[7]);
}

// ---- 2. prepcnt: W-pack (blocks 0,1) + degree/weight count by dst ---------

__global__ __launch_bounds__(256) void prepcnt_kernel(
    const int* __restrict__ dst, const float* __restrict__ ew,
    const float* __restrict__ W1, const float* __restrict__ W2,
    unsigned* __restrict__ Wt1, unsigned* __restrict__ Wt2,
    unsigned long long* __restrict__ degfx, int E)
{
    int t = threadIdx.x;
    if (blockIdx.x == 0) {
        for (int f = t; f < 128 * 64; f += 256) {
            int c = f % 128, j = f / 128;
            Wt1[c * 64 + j] = bf16r(W1[(size_t)(2 * j) * 128 + c]) |
                              (bf16r(W1[(size_t)(2 * j + 1) * 128 + c]) << 16);
        }
        return;
    }
    if (blockIdx.x == 1) {
        for (int f = t; f < 64 * 64; f += 256) {
            int c = f % 64, j = f / 64;
            Wt2[c * 64 + j] = bf16r(W2[(size_t)(2 * j) * 64 + c]) |
                              (bf16r(W2[(size_t)(2 * j + 1) * 64 + c]) << 16);
        }
        return;
    }
    int e0 = (blockIdx.x - 2) * 2048;
#pragma unroll
    for (int j = 0; j < 8; ++j) {
        int idx = e0 + t + j * 256;
        if (idx < E) {
            unsigned fx = (unsigned)__float2uint_rn(ew[idx] * 16777216.0f);
            atomicAdd(&degfx[dst[idx]], (1ull << 32) | (unsigned long long)fx);
        }
    }
}

// ---- 3. scanN: per-bucket scan -> dinv, nodeinfo, cur=0 -------------------

__global__ __launch_bounds__(512) void scanN_kernel(
    const unsigned long long* __restrict__ degfx, float* __restrict__ dinv,
    uint2* __restrict__ nodeinfo, int* __restrict__ cur, int N)
{
    __shared__ int scn[BNODES];
    int b = blockIdx.x, t = threadIdx.x;
    int gn = b * BNODES + t;
    unsigned long long v = (gn < N) ? degfx[gn] : 0ull;
    int cnt = (int)(v >> 32);
    float dv = rsqrtf((float)(unsigned)(v & 0xffffffffull) * (1.0f / 16777216.0f) + 1.0f);
    scn[t] = cnt;
    __syncthreads();
#pragma unroll
    for (int off = 1; off < BNODES; off <<= 1) {
        int a = (t >= off) ? scn[t - off] : 0;
        __syncthreads();
        scn[t] += a;
        __syncthreads();
    }
    int excl = scn[t] - cnt;
    if (gn < N) {
        dinv[gn] = dv;
        nodeinfo[gn] = make_uint2((unsigned)(b * CAP + excl), (unsigned)cnt);
        cur[gn] = 0;
    }
}

// ---- 5. scatter: direct CSR build via per-node cursors --------------------

__global__ __launch_bounds__(256) void scatter_kernel(
    const int* __restrict__ src, const int* __restrict__ dst,
    const float* __restrict__ ew, const unsigned* __restrict__ nodebase,
    int* __restrict__ cur, uint2* __restrict__ csrF, int E)
{
    int e0 = blockIdx.x * 2048;
    int t = threadIdx.x;
#pragma unroll
    for (int j = 0; j < 8; ++j) {
        int idx = e0 + t + j * 256;
        if (idx < E) {
            int d = dst[idx];
            unsigned base = nodebase[(size_t)d * 2];   // nodeinfo[d].x
            int p = atomicAdd(&cur[d], 1);
            csrF[base + p] = make_uint2((unsigned)src[idx], __float_as_uint(ew[idx]));
        }
    }
}

// ---- 4. gemm1: h1s = dinv * (x @ W1), bf16-packed -------------------------

__global__ __launch_bounds__(256) void gemm1_kernel(
    const float* __restrict__ Xf, const unsigned* __restrict__ Wt,
    const float* __restrict__ dinv, unsigned* __restrict__ Hb, int M)
{
    constexpr int LW = 68, KU = 64;
    __shared__ unsigned sA[64 * LW];
    __shared__ unsigned sB[128 * LW];
    __shared__ float sD[64];
    const int t = threadIdx.x;
    const int rbase = blockIdx.x * 64;

    if (t < 64) sD[t] = (rbase + t < M) ? dinv[rbase + t] : 0.f;
    for (int f = t; f < 128 * 16; f += 256) {       // B: 128 rows x 16 uint4
        int c = f >> 4, qd = f & 15;
        *(uint4*)&sB[c * LW + qd * 4] = *(const uint4*)&Wt[c * KU + qd * 4];
    }
    for (int f = t; f < 64 * 32; f += 256) {        // A: fp32 -> bf16 pack
        int r = f >> 5, c4 = f & 31;
        int gr = rbase + r;
        float4 v = make_float4(0.f, 0.f, 0.f, 0.f);
        if (gr < M) v = *(const float4*)&Xf[(size_t)gr * 128 + c4 * 4];
        sA[r * LW + c4 * 2]     = bf16r(v.x) | (bf16r(v.y) << 16);
        sA[r * LW + c4 * 2 + 1] = bf16r(v.z) | (bf16r(v.w) << 16);
    }
    __syncthreads();

    const int wave = t >> 6, lane = t & 63;
    const int quad = lane >> 4, lr = lane & 15;
    const int n0 = wave * 32;

    f32x4 acc[4][2];
#pragma unroll
    for (int mi = 0; mi < 4; ++mi)
#pragma unroll
        for (int ni = 0; ni < 2; ++ni)
            acc[mi][ni] = (f32x4){0.f, 0.f, 0.f, 0.f};

#pragma unroll
    for (int ks = 0; ks < 4; ++ks) {
        int ko = ks * 16 + quad * 4;
        bf16x8 b0 = *(const bf16x8*)&sB[(n0 + lr) * LW + ko];
        bf16x8 b1 = *(const bf16x8*)&sB[(n0 + 16 + lr) * LW + ko];
#pragma unroll
        for (int mi = 0; mi < 4; ++mi) {
            bf16x8 a = *(const bf16x8*)&sA[(mi * 16 + lr) * LW + ko];
            acc[mi][0] = __builtin_amdgcn_mfma_f32_16x16x32_bf16(a, b0, acc[mi][0], 0, 0, 0);
            acc[mi][1] = __builtin_amdgcn_mfma_f32_16x16x32_bf16(a, b1, acc[mi][1], 0, 0, 0);
        }
    }
    __syncthreads();

    unsigned short* sO = (unsigned short*)sA;       // [64][2*LW]
#pragma unroll
    for (int mi = 0; mi < 4; ++mi)
#pragma unroll
        for (int ni = 0; ni < 2; ++ni)
#pragma unroll
            for (int r = 0; r < 4; ++r) {
                int row = mi * 16 + quad * 4 + r;
                sO[row * (2 * LW) + n0 + ni * 16 + lr] =
                    (unsigned short)bf16r(acc[mi][ni][r] * sD[row]);
            }
    __syncthreads();

    for (int f = t; f < 64 * 64; f += 256) {
        int row = f >> 6, cu = f & 63;
        int gr = rbase + row;
        if (gr < M) Hb[(size_t)gr * 64 + cu] = sA[row * LW + cu];
    }
}

// ---- 6. gg: gather h1s (+scale+bias+relu) + MFMA gemm2, h2s row-scaled ----
// 512 thr / 8 waves, 16 nodes.  Each wave: TWO nodes interleaved with a
// depth-1 software-pipelined row prefetch (R10 structure, verbatim).

__global__ __launch_bounds__(512, 4) void gg_kernel(
    const uint2* __restrict__ nodeinfo, const uint2* __restrict__ csr,
    const uint4* __restrict__ Hb4,                 // h1s row = 16 uint4
    const float* __restrict__ dinv, const float* __restrict__ bias,
    const unsigned* __restrict__ Wt2, unsigned* __restrict__ H2, int N)
{
    __shared__ __align__(16) unsigned sG[16 * 68];   // g1 tile bf16-packed
    __shared__ __align__(16) float    sO[16 * 68];   // h2 fp32 tile
    __shared__ float sDi[16];

    const int t = threadIdx.x, wave = t >> 6, lane = t & 63;
    const int q = lane >> 4, cg = lane & 15;
    const int nb = blockIdx.x * 16;
    if (t < 16) sDi[t] = dinv[nb + t];

    const int m0 = wave * 2, m1 = m0 + 1;
    const int n0 = nb + m0, n1 = nb + m1;    // 6250*16 == 100000: no tail

    float one0 = (q == 0) ? 1.f : 0.f;       // self-loop weight 1 (hs has dinv)
    float acc0[8], acc1[8];
    {
        uint4 su = Hb4[(size_t)n0 * 16 + cg];
        uint4 sv = Hb4[(size_t)n1 * 16 + cg];
        acc0[0] = bf_lo(su.x) * one0; acc0[1] = bf_hi(su.x) * one0;
        acc0[2] = bf_lo(su.y) * one0; acc0[3] = bf_hi(su.y) * one0;
        acc0[4] = bf_lo(su.z) * one0; acc0[5] = bf_hi(su.z) * one0;
        acc0[6] = bf_lo(su.w) * one0; acc0[7] = bf_hi(su.w) * one0;
        acc1[0] = bf_lo(sv.x) * one0; acc1[1] = bf_hi(sv.x) * one0;
        acc1[2] = bf_lo(sv.y) * one0; acc1[3] = bf_hi(sv.y) * one0;
        acc1[4] = bf_lo(sv.z) * one0; acc1[5] = bf_hi(sv.z) * one0;
        acc1[6] = bf_lo(sv.w) * one0; acc1[7] = bf_hi(sv.w) * one0;
    }
    uint2 i0 = nodeinfo[n0], i1 = nodeinfo[n1];
    int j0 = (int)i0.x, e0v = j0 + (int)i0.y;
    int j1 = (int)i1.x, e1v = j1 + (int)i1.y;

    while (j0 < e0v || j1 < e1v) {
        int cs0 = 0, cs1 = 0; float cw0 = 0.f, cw1 = 0.f;
        if (j0 + lane < e0v) { uint2 p = csr[j0 + lane]; cs0 = (int)p.x; cw0 = __uint_as_float(p.y); }
        if (j1 + lane < e1v) { uint2 p = csr[j1 + lane]; cs1 = (int)p.x; cw1 = __uint_as_float(p.y); }
        int r0 = e0v - j0; int mm0 = r0 < 0 ? 0 : (r0 > 64 ? 64 : r0);
        int r1 = e1v - j1; int mm1 = r1 < 0 ? 0 : (r1 > 64 ? 64 : r1);
        int mmx = mm0 > mm1 ? mm0 : mm1;

        // prologue: slot q of both nodes (cs/cw are 0 beyond each node's mm,
        // so the short node degenerates to cached row-0 loads with w=0)
        int   s0 = __shfl(cs0, q),  s1 = __shfl(cs1, q);
        float w0 = __shfl(cw0, q),  w1 = __shfl(cw1, q);
        uint4 u0 = Hb4[(size_t)s0 * 16 + cg];
        uint4 u1 = Hb4[(size_t)s1 * 16 + cg];

        for (int k = 0; k < mmx; k += 4) {
            uint4 u0n = u0, u1n = u1;
            float w0n = 0.f, w1n = 0.f;
            if (k + 4 < mmx) {                     // wave-uniform
                int s0n = __shfl(cs0, k + 4 + q), s1n = __shfl(cs1, k + 4 + q);
                w0n = __shfl(cw0, k + 4 + q);     w1n = __shfl(cw1, k + 4 + q);
                u0n = Hb4[(size_t)s0n * 16 + cg];
                u1n = Hb4[(size_t)s1n * 16 + cg];
            }
            fma8(acc0, u0, w0);
            fma8(acc1, u1, w1);
            u0 = u0n; u1 = u1n; w0 = w0n; w1 = w1n;
        }
        j0 += 64; j1 += 64;
    }

#pragma unroll
    for (int v = 0; v < 8; ++v) {
        acc0[v] += __shfl_xor(acc0[v], 16);
        acc0[v] += __shfl_xor(acc0[v], 32);
        acc1[v] += __shfl_xor(acc1[v], 16);
        acc1[v] += __shfl_xor(acc1[v], 32);
    }
    if (q == 0) {
        int c = cg * 8;
        float di0 = dinv[n0];
        uint4 pk;
        pk.x = bf16r(fmaxf(acc0[0] * di0 + bias[c + 0], 0.f)) |
               (bf16r(fmaxf(acc0[1] * di0 + bias[c + 1], 0.f)) << 16);
        pk.y = bf16r(fmaxf(acc0[2] * di0 + bias[c + 2], 0.f)) |
               (bf16r(fmaxf(acc0[3] * di0 + bias[c + 3], 0.f)) << 16);
        pk.z = bf16r(fmaxf(acc0[4] * di0 + bias[c + 4], 0.f)) |
               (bf16r(fmaxf(acc0[5] * di0 + bias[c + 5], 0.f)) << 16);
        pk.w = bf16r(fmaxf(acc0[6] * di0 + bias[c + 6], 0.f)) |
               (bf16r(fmaxf(acc0[7] * di0 + bias[c + 7], 0.f)) << 16);
        *(uint4*)&sG[m0 * 68 + cg * 4] = pk;
        float di1 = dinv[n1];
        pk.x = bf16r(fmaxf(acc1[0] * di1 + bias[c + 0], 0.f)) |
               (bf16r(fmaxf(acc1[1] * di1 + bias[c + 1], 0.f)) << 16);
        pk.y = bf16r(fmaxf(acc1[2] * di1 + bias[c + 2], 0.f)) |
               (bf16r(fmaxf(acc1[3] * di1 + bias[c + 3], 0.f)) << 16);
        pk.z = bf16r(fmaxf(acc1[4] * di1 + bias[c + 4], 0.f)) |
               (bf16r(fmaxf(acc1[5] * di1 + bias[c + 5], 0.f)) << 16);
        pk.w = bf16r(fmaxf(acc1[6] * di1 + bias[c + 6], 0.f)) |
               (bf16r(fmaxf(acc1[7] * di1 + bias[c + 7], 0.f)) << 16);
        *(uint4*)&sG[m1 * 68 + cg * 4] = pk;
    }
    __syncthreads();

    // h2 tile: waves 0..3 each compute n-tile n0 = wave*16
    if (wave < 4) {
        const int quad = lane >> 4, lr = lane & 15;
        const int nt0 = wave * 16;
        f32x4 accv = (f32x4){0.f, 0.f, 0.f, 0.f};
#pragma unroll
        for (int ks = 0; ks < 4; ++ks) {
            int ko = ks * 16 + quad * 4;
            bf16x8 av = *(const bf16x8*)&sG[lr * 68 + ko];
            bf16x8 bv = *(const bf16x8*)&Wt2[(nt0 + lr) * 64 + ko];
            accv = __builtin_amdgcn_mfma_f32_16x16x32_bf16(av, bv, accv, 0, 0, 0);
        }
#pragma unroll
        for (int r = 0; r < 4; ++r)
            sO[(quad * 4 + r) * 68 + nt0 + lr] = accv[r];
    }
    __syncthreads();

    if (t < 512) {                         // 16 rows x 32 packed uints
        int row = t >> 5, cu = t & 31;
        float sc = sDi[row];               // h2s = dinv * h2
        unsigned pk = bf16r(sO[row * 68 + 2 * cu] * sc) |
                      (bf16r(sO[row * 68 + 2 * cu + 1] * sc) << 16);
        H2[(size_t)(nb + row) * 32 + cu] = pk;
    }
}

// ---- 7. gather64: aggregate h2s -> out fp32 -------------------------------
// 256 thr / 4 waves, 8 nodes per block (2 per wave, pipelined).  R10 verbatim.

__global__ __launch_bounds__(256, 4) void gather64_kernel(
    const uint2* __restrict__ nodeinfo, const uint2* __restrict__ csr,
    const uint4* __restrict__ Hb4,                 // h2s row = 8 uint4
    const float* __restrict__ dinv, const float* __restrict__ bias,
    float* __restrict__ OUT, int N)
{
    const int wave = threadIdx.x >> 6, lane = threadIdx.x & 63;
    const int n0 = blockIdx.x * 8 + wave * 2, n1 = n0 + 1;
    if (n0 >= N) return;                   // N even: n1 valid whenever n0 is
    const int q  = lane >> 3;              // slot 0..7
    const int cg = lane & 7;

    float one0 = (q == 0) ? 1.f : 0.f;
    float acc0[8], acc1[8];
    {
        uint4 su = Hb4[(size_t)n0 * 8 + cg];
        uint4 sv = Hb4[(size_t)n1 * 8 + cg];
        acc0[0] = bf_lo(su.x) * one0; acc0[1] = bf_hi(su.x) * one0;
        acc0[2] = bf_lo(su.y) * one0; acc0[3] = bf_hi(su.y) * one0;
        acc0[4] = bf_lo(su.z) * one0; acc0[5] = bf_hi(su.z) * one0;
        acc0[6] = bf_lo(su.w) * one0; acc0[7] = bf_hi(su.w) * one0;
        acc1[0] = bf_lo(sv.x) * one0; acc1[1] = bf_hi(sv.x) * one0;
        acc1[2] = bf_lo(sv.y) * one0; acc1[3] = bf_hi(sv.y) * one0;
        acc1[4] = bf_lo(sv.z) * one0; acc1[5] = bf_hi(sv.z) * one0;
        acc1[6] = bf_lo(sv.w) * one0; acc1[7] = bf_hi(sv.w) * one0;
    }

    uint2 i0 = nodeinfo[n0], i1 = nodeinfo[n1];
    int j0 = (int)i0.x, e0v = j0 + (int)i0.y;
    int j1 = (int)i1.x, e1v = j1 + (int)i1.y;

    while (j0 < e0v || j1 < e1v) {
        int cs0 = 0, cs1 = 0; float cw0 = 0.f, cw1 = 0.f;
        if (j0 + lane < e0v) { uint2 p = csr[j0 + lane]; cs0 = (int)p.x; cw0 = __uint_as_float(p.y); }
        if (j1 + lane < e1v) { uint2 p = csr[j1 + lane]; cs1 = (int)p.x; cw1 = __uint_as_float(p.y); }
        int r0 = e0v - j0; int mm0 = r0 < 0 ? 0 : (r0 > 64 ? 64 : r0);
        int r1 = e1v - j1; int mm1 = r1 < 0 ? 0 : (r1 > 64 ? 64 : r1);
        int mmx = mm0 > mm1 ? mm0 : mm1;

        int   s0 = __shfl(cs0, q),  s1 = __shfl(cs1, q);
        float w0 = __shfl(cw0, q),  w1 = __shfl(cw1, q);
        uint4 u0 = Hb4[(size_t)s0 * 8 + cg];
        uint4 u1 = Hb4[(size_t)s1 * 8 + cg];

        for (int k = 0; k < mmx; k += 8) {
            uint4 u0n = u0, u1n = u1;
            float w0n = 0.f, w1n = 0.f;
            if (k + 8 < mmx) {                     // wave-uniform
                int s0n = __shfl(cs0, k + 8 + q), s1n = __shfl(cs1, k + 8 + q);
                w0n = __shfl(cw0, k + 8 + q);     w1n = __shfl(cw1, k + 8 + q);
                u0n = Hb4[(size_t)s0n * 8 + cg];
                u1n = Hb4[(size_t)s1n * 8 + cg];
            }
            fma8(acc0, u0, w0);
            fma8(acc1, u1, w1);
            u0 = u0n; u1 = u1n; w0 = w0n; w1 = w1n;
        }
        j0 += 64; j1 += 64;
    }

#pragma unroll
    for (int v = 0; v < 8; ++v) {
        acc0[v] += __shfl_xor(acc0[v], 8);
        acc0[v] += __shfl_xor(acc0[v], 16);
        acc0[v] += __shfl_xor(acc0[v], 32);
        acc1[v] += __shfl_xor(acc1[v], 8);
        acc1[v] += __shfl_xor(acc1[v], 16);
        acc1[v] += __shfl_xor(acc1[v], 32);
    }

    int c = cg * 8 + q;
    OUT[(size_t)n0 * 64 + c] = acc0[q] * dinv[n0] + bias[c];
    OUT[(size_t)n1 * 64 + c] = acc1[q] * dinv[n1] + bias[c];
}

static inline size_t align_up(size_t x) { return (x + 255) & ~size_t(255); }

extern "C" void kernel_launch(void* const* d_in, const int* in_sizes, int n_in,
                              void* d_out, int out_size, void* d_ws, size_t ws_size,
                              hipStream_t stream)
{
    const float* x  = (const float*)d_in[0];
    const int*   ei = (const int*)d_in[1];
    const float* ew = (const float*)d_in[2];
    const float* W1 = (const float*)d_in[3];
    const float* b1 = (const float*)d_in[4];
    const float* W2 = (const float*)d_in[5];
    const float* b2 = (const float*)d_in[6];
    float* out = (float*)d_out;

    const int N = N_NODES;
    const int E = in_sizes[2];
    const int* src = ei;
    const int* dst = ei + E;

    const size_t REGION = (size_t)NBUCK * CAP;
    const int EBLK = (E + 2047) / 2048;

    char* ws = (char*)d_ws;
    unsigned long long* degfx = (unsigned long long*)ws; ws += align_up((size_t)N * 8);
    int*   cur       = (int*)ws;   ws += align_up((size_t)N * 4);
    float* dinv      = (float*)ws; ws += align_up((size_t)N * 4);
    uint2* nodeinfo  = (uint2*)ws; ws += align_up((size_t)N * 8);
    uint2* csrF      = (uint2*)ws; ws += align_up(REGION * 8);
    unsigned* Wt1    = (unsigned*)ws; ws += align_up((size_t)128 * 64 * 4);
    unsigned* Wt2    = (unsigned*)ws; ws += align_up((size_t)64 * 64 * 4);
    unsigned* h1     = (unsigned*)ws; ws += align_up((size_t)N * 64 * 4);  // h1s bf16 pk
    unsigned* h2     = (unsigned*)ws; ws += align_up((size_t)N * 32 * 4);  // h2s bf16 pk

    hipMemsetAsync(degfx, 0, (size_t)N * 8, stream);
    prepcnt_kernel<<<EBLK + 2, 256, 0, stream>>>(dst, ew, W1, W2, Wt1, Wt2, degfx, E);
    scanN_kernel<<<NBUCK, 512, 0, stream>>>(degfx, dinv, nodeinfo, cur, N);
    gemm1_kernel<<<(N + 63) / 64, 256, 0, stream>>>(x, Wt1, dinv, h1, N);
    scatter_kernel<<<EBLK, 256, 0, stream>>>(src, dst, ew, (const unsigned*)nodeinfo,
                                             cur, csrF, E);
    gg_kernel<<<N / 16, 512, 0, stream>>>(nodeinfo, csrF, (const uint4*)h1,
                                          dinv, b1, Wt2, h2, N);
    gather64_kernel<<<(N + 7) / 8, 256, 0, stream>>>(
        nodeinfo, csrF, (const uint4*)h2, dinv, b2, out, N);
}

// Round 5
// 273.850 us; speedup vs baseline: 1.4140x; 1.4140x over previous
//
#include <hip/hip_runtime.h>

// ---------------------------------------------------------------------------
// Two-layer GCN on MI355X.  Round 14: restore R10/R1 optimum configuration.
//   Measured lesson ledger:
//     - per-quad broadcast csr loads: -23% (R11). coalesced batch + shfl wins.
//     - depth-3 unrolled gather pipeline: -25% occupancy collapse (R12).
//     - global-atomic CSR build: 8x write amplification, scatter=90us (R13).
//   This is the empirically best combination: LDS-radix prep + depth-1
//   2-node pipelined gathers.
//   Pipeline (7 dispatches):
//     1. prepA1  : W1/W2 bf16 B-layout pack + per-block dst histogram
//     2. scanB   : per-bucket scan over blocks
//     3. a2      : bucket-reorder edges -> csrTmp
//     4. bucketB : per-bucket dinv, nodeinfo, node-sorted csrF={s,ew}
//     5. gemm1   : h1s = dinv*(x@W1)  (MFMA, row-scaled epilogue)
//     6. gg      : gather(ew) + bias/relu + MFMA gemm2, h2s = dinv*h2
//     7. gather64: gather(ew) + final scale + bias -> out fp32
// ---------------------------------------------------------------------------

#define N_NODES 100000
#define CHUNK   2048
#define NBUCK   196
#define BSHIFT  9
#define BNODES  512
#define CAP     10240

typedef __attribute__((ext_vector_type(8))) short bf16x8;
typedef __attribute__((ext_vector_type(4))) float f32x4;

__device__ __forceinline__ unsigned bf16r(float f) {
    unsigned u = __float_as_uint(f);
    return (u + 0x7fffu + ((u >> 16) & 1u)) >> 16;     // RNE
}
__device__ __forceinline__ float bf_lo(unsigned u) { return __uint_as_float(u << 16); }
__device__ __forceinline__ float bf_hi(unsigned u) { return __uint_as_float(u & 0xffff0000u); }

__device__ __forceinline__ void fma8(float* a, uint4 u, float w) {
    a[0] = fmaf(bf_lo(u.x), w, a[0]); a[1] = fmaf(bf_hi(u.x), w, a[1]);
    a[2] = fmaf(bf_lo(u.y), w, a[2]); a[3] = fmaf(bf_hi(u.y), w, a[3]);
    a[4] = fmaf(bf_lo(u.z), w, a[4]); a[5] = fmaf(bf_hi(u.z), w, a[5]);
    a[6] = fmaf(bf_lo(u.w), w, a[6]); a[7] = fmaf(bf_hi(u.w), w, a[7]);
}

// ---- 1. prepA1: W-pack (blocks 0,1) + per-block bucket histogram ----------

__global__ __launch_bounds__(256) void prepA1_kernel(
    const int* __restrict__ dst, const float* __restrict__ W1,
    const float* __restrict__ W2, unsigned* __restrict__ Wt1,
    unsigned* __restrict__ Wt2, int* __restrict__ histmat, int E)
{
    __shared__ int hist[256];
    int t = threadIdx.x;
    if (blockIdx.x == 0) {
        for (int f = t; f < 128 * 64; f += 256) {
            int c = f % 128, j = f / 128;
            Wt1[c * 64 + j] = bf16r(W1[(size_t)(2 * j) * 128 + c]) |
                              (bf16r(W1[(size_t)(2 * j + 1) * 128 + c]) << 16);
        }
        return;
    }
    if (blockIdx.x == 1) {
        for (int f = t; f < 64 * 64; f += 256) {
            int c = f % 64, j = f / 64;
            Wt2[c * 64 + j] = bf16r(W2[(size_t)(2 * j) * 64 + c]) |
                              (bf16r(W2[(size_t)(2 * j + 1) * 64 + c]) << 16);
        }
        return;
    }
    int blk = blockIdx.x - 2;
    hist[t] = 0;
    __syncthreads();
    int e0 = blk * CHUNK;
    int nv = min(CHUNK, E - e0);
#pragma unroll
    for (int j = 0; j < CHUNK / 256; ++j) {
        int idx = t + j * 256;
        if (idx < nv) atomicAdd(&hist[dst[e0 + idx] >> BSHIFT], 1);
    }
    __syncthreads();
    histmat[blk * 256 + t] = hist[t];
}

// ---- 2. scanB -------------------------------------------------------------

__global__ __launch_bounds__(256) void scanB_kernel(
    int* __restrict__ histmat, int* __restrict__ bucketSize, int NBLK)
{
    __shared__ int sums[256];
    int b = blockIdx.x, t = threadIdx.x;
    const int PER = (NBLK + 255) / 256;
    int loc[8];
    int s = 0;
#pragma unroll 8
    for (int j = 0; j < PER; ++j) {
        int r = t * PER + j;
        int v = (r < NBLK) ? histmat[r * 256 + b] : 0;
        loc[j] = v; s += v;
    }
    sums[t] = s;
    __syncthreads();
    int v = s;
#pragma unroll
    for (int off = 1; off < 256; off <<= 1) {
        int a = (t >= off) ? sums[t - off] : 0;
        __syncthreads();
        sums[t] += a;
        __syncthreads();
    }
    if (t == 255) bucketSize[b] = sums[255];
    int run = sums[t] - v;
#pragma unroll 8
    for (int j = 0; j < PER; ++j) {
        int r = t * PER + j;
        if (r < NBLK) { histmat[r * 256 + b] = run; run += loc[j]; }
    }
}

// ---- 3. a2: reorder block's edges by bucket, write grouped runs -----------

__global__ __launch_bounds__(256) void a2_kernel(
    const int* __restrict__ src, const int* __restrict__ dst,
    const float* __restrict__ ew, const int* __restrict__ histmat,
    uint2* __restrict__ csrTmp, int E)
{
    __shared__ int hist[256], sc[256], exc[256], lcur[256], basel[256];
    __shared__ uint2 ent[CHUNK];
    __shared__ unsigned short bof[CHUNK];

    int t = threadIdx.x, blk = blockIdx.x;
    hist[t] = 0; lcur[t] = 0;
    basel[t] = histmat[blk * 256 + t];
    __syncthreads();

    int e0 = blk * CHUNK;
    int nv = min(CHUNK, E - e0);
    int dv[CHUNK / 256]; int sv[CHUNK / 256]; unsigned wv[CHUNK / 256];
#pragma unroll
    for (int j = 0; j < CHUNK / 256; ++j) {
        int idx = t + j * 256;
        if (idx < nv) {
            int e = e0 + idx;
            dv[j] = dst[e]; sv[j] = src[e]; wv[j] = __float_as_uint(ew[e]);
            atomicAdd(&hist[dv[j] >> BSHIFT], 1);
        } else dv[j] = -1;
    }
    __syncthreads();
    int hv = hist[t];
    sc[t] = hv;
    __syncthreads();
#pragma unroll
    for (int off = 1; off < 256; off <<= 1) {
        int a = (t >= off) ? sc[t - off] : 0;
        __syncthreads();
        sc[t] += a;
        __syncthreads();
    }
    exc[t] = sc[t] - hv;
    __syncthreads();
#pragma unroll
    for (int j = 0; j < CHUNK / 256; ++j) {
        if (dv[j] >= 0) {
            int b  = dv[j] >> BSHIFT;
            int dl = dv[j] & (BNODES - 1);
            int p  = exc[b] + atomicAdd(&lcur[b], 1);
            ent[p] = make_uint2(((unsigned)dl << 17) | (unsigned)sv[j], wv[j]);
            bof[p] = (unsigned short)b;
        }
    }
    __syncthreads();
#pragma unroll
    for (int j = 0; j < CHUNK / 256; ++j) {
        int i = t + j * 256;
        if (i < nv) {
            int b = bof[i];
            csrTmp[(size_t)b * CAP + basel[b] + (i - exc[b])] = ent[i];
        }
    }
}

// ---- 4. bucketB: dinv, nodeinfo, node-sorted csrF={s,ew} ------------------

__global__ __launch_bounds__(1024) void bucketB_kernel(
    const uint2* __restrict__ csrTmp, const int* __restrict__ bucketSize,
    float* __restrict__ dinv, uint2* __restrict__ nodeinfo,
    uint2* __restrict__ csrF, int N)
{
    __shared__ uint2 ent[CAP];
    __shared__ unsigned long long dc[BNODES];
    __shared__ int scn[BNODES], beg[BNODES], cur[BNODES];
    int b = blockIdx.x, t = threadIdx.x;
    if (t < BNODES) { dc[t] = 0ull; cur[t] = 0; }
    __syncthreads();

    int sz = min(bucketSize[b], CAP);
    const uint2* reg = csrTmp + (size_t)b * CAP;
    for (int i = t; i < sz; i += 1024) {
        uint2 en = reg[i];
        ent[i] = en;
        int dl = (int)(en.x >> 17);
        unsigned fx = (unsigned)__float2uint_rn(__uint_as_float(en.y) * 16777216.0f);
        atomicAdd(&dc[dl], (1ull << 32) | (unsigned long long)fx);
    }
    __syncthreads();

    int cnt = 0; float dv = 1.0f;
    if (t < BNODES) {
        unsigned long long v = dc[t];
        cnt = (int)(v >> 32);
        dv = rsqrtf((float)(unsigned)(v & 0xffffffffull) * (1.0f / 16777216.0f) + 1.0f);
        scn[t] = cnt;
    }
    __syncthreads();
#pragma unroll
    for (int off = 1; off < BNODES; off <<= 1) {
        int a = 0;
        if (t < BNODES && t >= off) a = scn[t - off];
        __syncthreads();
        if (t < BNODES) scn[t] += a;
        __syncthreads();
    }
    if (t < BNODES) {
        int excl = scn[t] - cnt;
        beg[t] = excl;
        int gn = b * BNODES + t;
        if (gn < N) {
            dinv[gn] = dv;
            nodeinfo[gn] = make_uint2((unsigned)(b * CAP + excl), (unsigned)cnt);
        }
    }
    __syncthreads();

    uint2* outreg = csrF + (size_t)b * CAP;
    for (int i = t; i < sz; i += 1024) {
        uint2 en = ent[i];
        int dl = (int)(en.x >> 17);
        int p  = beg[dl] + atomicAdd(&cur[dl], 1);
        outreg[p] = make_uint2(en.x & 0x1FFFFu, en.y);   // {src, ew}
    }
}

// ---- 5. gemm1: h1s = dinv * (x @ W1), bf16-packed -------------------------

__global__ __launch_bounds__(256) void gemm1_kernel(
    const float* __restrict__ Xf, const unsigned* __restrict__ Wt,
    const float* __restrict__ dinv, unsigned* __restrict__ Hb, int M)
{
    constexpr int LW = 68, KU = 64;
    __shared__ unsigned sA[64 * LW];
    __shared__ unsigned sB[128 * LW];
    __shared__ float sD[64];
    const int t = threadIdx.x;
    const int rbase = blockIdx.x * 64;

    if (t < 64) sD[t] = (rbase + t < M) ? dinv[rbase + t] : 0.f;
    for (int f = t; f < 128 * 16; f += 256) {       // B: 128 rows x 16 uint4
        int c = f >> 4, qd = f & 15;
        *(uint4*)&sB[c * LW + qd * 4] = *(const uint4*)&Wt[c * KU + qd * 4];
    }
    for (int f = t; f < 64 * 32; f += 256) {        // A: fp32 -> bf16 pack
        int r = f >> 5, c4 = f & 31;
        int gr = rbase + r;
        float4 v = make_float4(0.f, 0.f, 0.f, 0.f);
        if (gr < M) v = *(const float4*)&Xf[(size_t)gr * 128 + c4 * 4];
        sA[r * LW + c4 * 2]     = bf16r(v.x) | (bf16r(v.y) << 16);
        sA[r * LW + c4 * 2 + 1] = bf16r(v.z) | (bf16r(v.w) << 16);
    }
    __syncthreads();

    const int wave = t >> 6, lane = t & 63;
    const int quad = lane >> 4, lr = lane & 15;
    const int n0 = wave * 32;

    f32x4 acc[4][2];
#pragma unroll
    for (int mi = 0; mi < 4; ++mi)
#pragma unroll
        for (int ni = 0; ni < 2; ++ni)
            acc[mi][ni] = (f32x4){0.f, 0.f, 0.f, 0.f};

#pragma unroll
    for (int ks = 0; ks < 4; ++ks) {
        int ko = ks * 16 + quad * 4;
        bf16x8 b0 = *(const bf16x8*)&sB[(n0 + lr) * LW + ko];
        bf16x8 b1 = *(const bf16x8*)&sB[(n0 + 16 + lr) * LW + ko];
#pragma unroll
        for (int mi = 0; mi < 4; ++mi) {
            bf16x8 a = *(const bf16x8*)&sA[(mi * 16 + lr) * LW + ko];
            acc[mi][0] = __builtin_amdgcn_mfma_f32_16x16x32_bf16(a, b0, acc[mi][0], 0, 0, 0);
            acc[mi][1] = __builtin_amdgcn_mfma_f32_16x16x32_bf16(a, b1, acc[mi][1], 0, 0, 0);
        }
    }
    __syncthreads();

    unsigned short* sO = (unsigned short*)sA;       // [64][2*LW]
#pragma unroll
    for (int mi = 0; mi < 4; ++mi)
#pragma unroll
        for (int ni = 0; ni < 2; ++ni)
#pragma unroll
            for (int r = 0; r < 4; ++r) {
                int row = mi * 16 + quad * 4 + r;
                sO[row * (2 * LW) + n0 + ni * 16 + lr] =
                    (unsigned short)bf16r(acc[mi][ni][r] * sD[row]);
            }
    __syncthreads();

    for (int f = t; f < 64 * 64; f += 256) {
        int row = f >> 6, cu = f & 63;
        int gr = rbase + row;
        if (gr < M) Hb[(size_t)gr * 64 + cu] = sA[row * LW + cu];
    }
}

// ---- 6. gg: gather h1s (+scale+bias+relu) + MFMA gemm2, h2s row-scaled ----
// 512 thr / 8 waves, 16 nodes.  Each wave: TWO nodes interleaved with a
// depth-1 software-pipelined row prefetch (best measured form).

__global__ __launch_bounds__(512, 4) void gg_kernel(
    const uint2* __restrict__ nodeinfo, const uint2* __restrict__ csr,
    const uint4* __restrict__ Hb4,                 // h1s row = 16 uint4
    const float* __restrict__ dinv, const float* __restrict__ bias,
    const unsigned* __restrict__ Wt2, unsigned* __restrict__ H2, int N)
{
    __shared__ __align__(16) unsigned sG[16 * 68];   // g1 tile bf16-packed
    __shared__ __align__(16) float    sO[16 * 68];   // h2 fp32 tile
    __shared__ float sDi[16];

    const int t = threadIdx.x, wave = t >> 6, lane = t & 63;
    const int q = lane >> 4, cg = lane & 15;
    const int nb = blockIdx.x * 16;
    if (t < 16) sDi[t] = dinv[nb + t];

    const int m0 = wave * 2, m1 = m0 + 1;
    const int n0 = nb + m0, n1 = nb + m1;    // 6250*16 == 100000: no tail

    float one0 = (q == 0) ? 1.f : 0.f;       // self-loop weight 1 (hs has dinv)
    float acc0[8], acc1[8];
    {
        uint4 su = Hb4[(size_t)n0 * 16 + cg];
        uint4 sv = Hb4[(size_t)n1 * 16 + cg];
        acc0[0] = bf_lo(su.x) * one0; acc0[1] = bf_hi(su.x) * one0;
        acc0[2] = bf_lo(su.y) * one0; acc0[3] = bf_hi(su.y) * one0;
        acc0[4] = bf_lo(su.z) * one0; acc0[5] = bf_hi(su.z) * one0;
        acc0[6] = bf_lo(su.w) * one0; acc0[7] = bf_hi(su.w) * one0;
        acc1[0] = bf_lo(sv.x) * one0; acc1[1] = bf_hi(sv.x) * one0;
        acc1[2] = bf_lo(sv.y) * one0; acc1[3] = bf_hi(sv.y) * one0;
        acc1[4] = bf_lo(sv.z) * one0; acc1[5] = bf_hi(sv.z) * one0;
        acc1[6] = bf_lo(sv.w) * one0; acc1[7] = bf_hi(sv.w) * one0;
    }
    uint2 i0 = nodeinfo[n0], i1 = nodeinfo[n1];
    int j0 = (int)i0.x, e0v = j0 + (int)i0.y;
    int j1 = (int)i1.x, e1v = j1 + (int)i1.y;

    while (j0 < e0v || j1 < e1v) {
        int cs0 = 0, cs1 = 0; float cw0 = 0.f, cw1 = 0.f;
        if (j0 + lane < e0v) { uint2 p = csr[j0 + lane]; cs0 = (int)p.x; cw0 = __uint_as_float(p.y); }
        if (j1 + lane < e1v) { uint2 p = csr[j1 + lane]; cs1 = (int)p.x; cw1 = __uint_as_float(p.y); }
        int r0 = e0v - j0; int mm0 = r0 < 0 ? 0 : (r0 > 64 ? 64 : r0);
        int r1 = e1v - j1; int mm1 = r1 < 0 ? 0 : (r1 > 64 ? 64 : r1);
        int mmx = mm0 > mm1 ? mm0 : mm1;

        // prologue: slot q of both nodes (cs/cw are 0 beyond each node's mm,
        // so the short node degenerates to cached row-0 loads with w=0)
        int   s0 = __shfl(cs0, q),  s1 = __shfl(cs1, q);
        float w0 = __shfl(cw0, q),  w1 = __shfl(cw1, q);
        uint4 u0 = Hb4[(size_t)s0 * 16 + cg];
        uint4 u1 = Hb4[(size_t)s1 * 16 + cg];

        for (int k = 0; k < mmx; k += 4) {
            uint4 u0n = u0, u1n = u1;
            float w0n = 0.f, w1n = 0.f;
            if (k + 4 < mmx) {                     // wave-uniform
                int s0n = __shfl(cs0, k + 4 + q), s1n = __shfl(cs1, k + 4 + q);
                w0n = __shfl(cw0, k + 4 + q);     w1n = __shfl(cw1, k + 4 + q);
                u0n = Hb4[(size_t)s0n * 16 + cg];
                u1n = Hb4[(size_t)s1n * 16 + cg];
            }
            fma8(acc0, u0, w0);
            fma8(acc1, u1, w1);
            u0 = u0n; u1 = u1n; w0 = w0n; w1 = w1n;
        }
        j0 += 64; j1 += 64;
    }

#pragma unroll
    for (int v = 0; v < 8; ++v) {
        acc0[v] += __shfl_xor(acc0[v], 16);
        acc0[v] += __shfl_xor(acc0[v], 32);
        acc1[v] += __shfl_xor(acc1[v], 16);
        acc1[v] += __shfl_xor(acc1[v], 32);
    }
    if (q == 0) {
        int c = cg * 8;
        float di0 = dinv[n0];
        uint4 pk;
        pk.x = bf16r(fmaxf(acc0[0] * di0 + bias[c + 0], 0.f)) |
               (bf16r(fmaxf(acc0[1] * di0 + bias[c + 1], 0.f)) << 16);
        pk.y = bf16r(fmaxf(acc0[2] * di0 + bias[c + 2], 0.f)) |
               (bf16r(fmaxf(acc0[3] * di0 + bias[c + 3], 0.f)) << 16);
        pk.z = bf16r(fmaxf(acc0[4] * di0 + bias[c + 4], 0.f)) |
               (bf16r(fmaxf(acc0[5] * di0 + bias[c + 5], 0.f)) << 16);
        pk.w = bf16r(fmaxf(acc0[6] * di0 + bias[c + 6], 0.f)) |
               (bf16r(fmaxf(acc0[7] * di0 + bias[c + 7], 0.f)) << 16);
        *(uint4*)&sG[m0 * 68 + cg * 4] = pk;
        float di1 = dinv[n1];
        pk.x = bf16r(fmaxf(acc1[0] * di1 + bias[c + 0], 0.f)) |
               (bf16r(fmaxf(acc1[1] * di1 + bias[c + 1], 0.f)) << 16);
        pk.y = bf16r(fmaxf(acc1[2] * di1 + bias[c + 2], 0.f)) |
               (bf16r(fmaxf(acc1[3] * di1 + bias[c + 3], 0.f)) << 16);
        pk.z = bf16r(fmaxf(acc1[4] * di1 + bias[c + 4], 0.f)) |
               (bf16r(fmaxf(acc1[5] * di1 + bias[c + 5], 0.f)) << 16);
        pk.w = bf16r(fmaxf(acc1[6] * di1 + bias[c + 6], 0.f)) |
               (bf16r(fmaxf(acc1[7] * di1 + bias[c + 7], 0.f)) << 16);
        *(uint4*)&sG[m1 * 68 + cg * 4] = pk;
    }
    __syncthreads();

    // h2 tile: waves 0..3 each compute n-tile n0 = wave*16
    if (wave < 4) {
        const int quad = lane >> 4, lr = lane & 15;
        const int nt0 = wave * 16;
        f32x4 accv = (f32x4){0.f, 0.f, 0.f, 0.f};
#pragma unroll
        for (int ks = 0; ks < 4; ++ks) {
            int ko = ks * 16 + quad * 4;
            bf16x8 av = *(const bf16x8*)&sG[lr * 68 + ko];
            bf16x8 bv = *(const bf16x8*)&Wt2[(nt0 + lr) * 64 + ko];
            accv = __builtin_amdgcn_mfma_f32_16x16x32_bf16(av, bv, accv, 0, 0, 0);
        }
#pragma unroll
        for (int r = 0; r < 4; ++r)
            sO[(quad * 4 + r) * 68 + nt0 + lr] = accv[r];
    }
    __syncthreads();

    if (t < 512) {                         // 16 rows x 32 packed uints
        int row = t >> 5, cu = t & 31;
        float sc = sDi[row];               // h2s = dinv * h2
        unsigned pk = bf16r(sO[row * 68 + 2 * cu] * sc) |
                      (bf16r(sO[row * 68 + 2 * cu + 1] * sc) << 16);
        H2[(size_t)(nb + row) * 32 + cu] = pk;
    }
}

// ---- 7. gather64: aggregate h2s -> out fp32 -------------------------------
// 256 thr / 4 waves, 8 nodes per block (2 per wave, pipelined).

__global__ __launch_bounds__(256, 4) void gather64_kernel(
    const uint2* __restrict__ nodeinfo, const uint2* __restrict__ csr,
    const uint4* __restrict__ Hb4,                 // h2s row = 8 uint4
    const float* __restrict__ dinv, const float* __restrict__ bias,
    float* __restrict__ OUT, int N)
{
    const int wave = threadIdx.x >> 6, lane = threadIdx.x & 63;
    const int n0 = blockIdx.x * 8 + wave * 2, n1 = n0 + 1;
    if (n0 >= N) return;                   // N even: n1 valid whenever n0 is
    const int q  = lane >> 3;              // slot 0..7
    const int cg = lane & 7;

    float one0 = (q == 0) ? 1.f : 0.f;
    float acc0[8], acc1[8];
    {
        uint4 su = Hb4[(size_t)n0 * 8 + cg];
        uint4 sv = Hb4[(size_t)n1 * 8 + cg];
        acc0[0] = bf_lo(su.x) * one0; acc0[1] = bf_hi(su.x) * one0;
        acc0[2] = bf_lo(su.y) * one0; acc0[3] = bf_hi(su.y) * one0;
        acc0[4] = bf_lo(su.z) * one0; acc0[5] = bf_hi(su.z) * one0;
        acc0[6] = bf_lo(su.w) * one0; acc0[7] = bf_hi(su.w) * one0;
        acc1[0] = bf_lo(sv.x) * one0; acc1[1] = bf_hi(sv.x) * one0;
        acc1[2] = bf_lo(sv.y) * one0; acc1[3] = bf_hi(sv.y) * one0;
        acc1[4] = bf_lo(sv.z) * one0; acc1[5] = bf_hi(sv.z) * one0;
        acc1[6] = bf_lo(sv.w) * one0; acc1[7] = bf_hi(sv.w) * one0;
    }

    uint2 i0 = nodeinfo[n0], i1 = nodeinfo[n1];
    int j0 = (int)i0.x, e0v = j0 + (int)i0.y;
    int j1 = (int)i1.x, e1v = j1 + (int)i1.y;

    while (j0 < e0v || j1 < e1v) {
        int cs0 = 0, cs1 = 0; float cw0 = 0.f, cw1 = 0.f;
        if (j0 + lane < e0v) { uint2 p = csr[j0 + lane]; cs0 = (int)p.x; cw0 = __uint_as_float(p.y); }
        if (j1 + lane < e1v) { uint2 p = csr[j1 + lane]; cs1 = (int)p.x; cw1 = __uint_as_float(p.y); }
        int r0 = e0v - j0; int mm0 = r0 < 0 ? 0 : (r0 > 64 ? 64 : r0);
        int r1 = e1v - j1; int mm1 = r1 < 0 ? 0 : (r1 > 64 ? 64 : r1);
        int mmx = mm0 > mm1 ? mm0 : mm1;

        int   s0 = __shfl(cs0, q),  s1 = __shfl(cs1, q);
        float w0 = __shfl(cw0, q),  w1 = __shfl(cw1, q);
        uint4 u0 = Hb4[(size_t)s0 * 8 + cg];
        uint4 u1 = Hb4[(size_t)s1 * 8 + cg];

        for (int k = 0; k < mmx; k += 8) {
            uint4 u0n = u0, u1n = u1;
            float w0n = 0.f, w1n = 0.f;
            if (k + 8 < mmx) {                     // wave-uniform
                int s0n = __shfl(cs0, k + 8 + q), s1n = __shfl(cs1, k + 8 + q);
                w0n = __shfl(cw0, k + 8 + q);     w1n = __shfl(cw1, k + 8 + q);
                u0n = Hb4[(size_t)s0n * 8 + cg];
                u1n = Hb4[(size_t)s1n * 8 + cg];
            }
            fma8(acc0, u0, w0);
            fma8(acc1, u1, w1);
            u0 = u0n; u1 = u1n; w0 = w0n; w1 = w1n;
        }
        j0 += 64; j1 += 64;
    }

#pragma unroll
    for (int v = 0; v < 8; ++v) {
        acc0[v] += __shfl_xor(acc0[v], 8);
        acc0[v] += __shfl_xor(acc0[v], 16);
        acc0[v] += __shfl_xor(acc0[v], 32);
        acc1[v] += __shfl_xor(acc1[v], 8);
        acc1[v] += __shfl_xor(acc1[v], 16);
        acc1[v] += __shfl_xor(acc1[v], 32);
    }

    int c = cg * 8 + q;
    OUT[(size_t)n0 * 64 + c] = acc0[q] * dinv[n0] + bias[c];
    OUT[(size_t)n1 * 64 + c] = acc1[q] * dinv[n1] + bias[c];
}

static inline size_t align_up(size_t x) { return (x + 255) & ~size_t(255); }

extern "C" void kernel_launch(void* const* d_in, const int* in_sizes, int n_in,
                              void* d_out, int out_size, void* d_ws, size_t ws_size,
                              hipStream_t stream)
{
    const float* x  = (const float*)d_in[0];
    const int*   ei = (const int*)d_in[1];
    const float* ew = (const float*)d_in[2];
    const float* W1 = (const float*)d_in[3];
    const float* b1 = (const float*)d_in[4];
    const float* W2 = (const float*)d_in[5];
    const float* b2 = (const float*)d_in[6];
    float* out = (float*)d_out;

    const int N = N_NODES;
    const int E = in_sizes[2];
    const int* src = ei;
    const int* dst = ei + E;

    const int NBLK = (E + CHUNK - 1) / CHUNK;
    const size_t REGION = (size_t)NBUCK * CAP;

    char* ws = (char*)d_ws;
    int*   histmat   = (int*)ws;   ws += align_up((size_t)NBLK * 256 * 4);
    int*   bucketSize= (int*)ws;   ws += align_up((size_t)NBUCK * 4);
    float* dinv      = (float*)ws; ws += align_up((size_t)N * 4);
    uint2* nodeinfo  = (uint2*)ws; ws += align_up((size_t)N * 8);
    uint2* csrTmp    = (uint2*)ws; ws += align_up(REGION * 8);
    uint2* csrF      = (uint2*)ws; ws += align_up(REGION * 8);
    unsigned* Wt1    = (unsigned*)ws; ws += align_up((size_t)128 * 64 * 4);
    unsigned* Wt2    = (unsigned*)ws; ws += align_up((size_t)64 * 64 * 4);
    unsigned* h1     = (unsigned*)ws; ws += align_up((size_t)N * 64 * 4);  // h1s bf16 pk
    unsigned* h2     = (unsigned*)ws; ws += align_up((size_t)N * 32 * 4);  // h2s bf16 pk

    prepA1_kernel<<<NBLK + 2, 256, 0, stream>>>(dst, W1, W2, Wt1, Wt2, histmat, E);
    scanB_kernel<<<NBUCK, 256, 0, stream>>>(histmat, bucketSize, NBLK);
    a2_kernel<<<NBLK, 256, 0, stream>>>(src, dst, ew, histmat, csrTmp, E);
    bucketB_kernel<<<NBUCK, 1024, 0, stream>>>(csrTmp, bucketSize, dinv, nodeinfo, csrF, N);
    gemm1_kernel<<<(N + 63) / 64, 256, 0, stream>>>(x, Wt1, dinv, h1, N);
    gg_kernel<<<N / 16, 512, 0, stream>>>(nodeinfo, csrF, (const uint4*)h1,
                                          dinv, b1, Wt2, h2, N);
    gather64_kernel<<<(N + 7) / 8, 256, 0, stream>>>(
        nodeinfo, csrF, (const uint4*)h2, dinv, b2, out, N);
}

// Round 6
// 270.545 us; speedup vs baseline: 1.4312x; 1.0122x over previous
//
#include <hip/hip_runtime.h>

// ---------------------------------------------------------------------------
// Two-layer GCN on MI355X.  Round 15: fuse prep via bucket-cursor atomics.
//   Ledger: per-quad bcast loads -23% (R11); deep unroll pipeline -25% (R12);
//   per-EDGE global-atomic CSR build 8x write-amp (R13).  Gathers stay in
//   their measured-optimal R10 form.
//   New: prepA1-histogram + scanB deleted.  a2F reserves each block's
//   per-bucket run with ONE atomicAdd per (block,bucket) (~150K atomics on
//   196 L2-hot counters); bucketB re-sorts within bucket as before, so the
//   lost block-ordering is irrelevant.  W-pack folded into a2F blocks 0/1.
//   Pipeline (5 dispatches + memset):
//     0. memset  : bucketCur = 0
//     1. a2F     : W-pack + block-local bucket radix + atomic run reserve
//     2. bucketB : per-bucket dinv, nodeinfo, node-sorted csrF={s,ew}
//     3. gemm1   : h1s = dinv*(x@W1)  (MFMA, row-scaled epilogue)
//     4. gg      : gather(ew) + bias/relu + MFMA gemm2, h2s = dinv*h2
//     5. gather64: gather(ew) + final scale + bias -> out fp32
// ---------------------------------------------------------------------------

#define N_NODES 100000
#define CHUNK   2048
#define NBUCK   196
#define BSHIFT  9
#define BNODES  512
#define CAP     10240

typedef __attribute__((ext_vector_type(8))) short bf16x8;
typedef __attribute__((ext_vector_type(4))) float f32x4;

__device__ __forceinline__ unsigned bf16r(float f) {
    unsigned u = __float_as_uint(f);
    return (u + 0x7fffu + ((u >> 16) & 1u)) >> 16;     // RNE
}
__device__ __forceinline__ float bf_lo(unsigned u) { return __uint_as_float(u << 16); }
__device__ __forceinline__ float bf_hi(unsigned u) { return __uint_as_float(u & 0xffff0000u); }

__device__ __forceinline__ void fma8(float* a, uint4 u, float w) {
    a[0] = fmaf(bf_lo(u.x), w, a[0]); a[1] = fmaf(bf_hi(u.x), w, a[1]);
    a[2] = fmaf(bf_lo(u.y), w, a[2]); a[3] = fmaf(bf_hi(u.y), w, a[3]);
    a[4] = fmaf(bf_lo(u.z), w, a[4]); a[5] = fmaf(bf_hi(u.z), w, a[5]);
    a[6] = fmaf(bf_lo(u.w), w, a[6]); a[7] = fmaf(bf_hi(u.w), w, a[7]);
}

// ---- 1. a2F: W-pack (blocks 0,1) + bucket radix with atomic run reserve ---

__global__ __launch_bounds__(256) void a2F_kernel(
    const int* __restrict__ src, const int* __restrict__ dst,
    const float* __restrict__ ew, const float* __restrict__ W1,
    const float* __restrict__ W2, unsigned* __restrict__ Wt1,
    unsigned* __restrict__ Wt2, int* __restrict__ bucketCur,
    uint2* __restrict__ csrTmp, int E)
{
    __shared__ int hist[256], sc[256], exc[256], lcur[256], basel[256];
    __shared__ uint2 ent[CHUNK];
    __shared__ unsigned short bof[CHUNK];

    int t = threadIdx.x;
    if (blockIdx.x == 0) {
        for (int f = t; f < 128 * 64; f += 256) {
            int c = f % 128, j = f / 128;
            Wt1[c * 64 + j] = bf16r(W1[(size_t)(2 * j) * 128 + c]) |
                              (bf16r(W1[(size_t)(2 * j + 1) * 128 + c]) << 16);
        }
        return;
    }
    if (blockIdx.x == 1) {
        for (int f = t; f < 64 * 64; f += 256) {
            int c = f % 64, j = f / 64;
            Wt2[c * 64 + j] = bf16r(W2[(size_t)(2 * j) * 64 + c]) |
                              (bf16r(W2[(size_t)(2 * j + 1) * 64 + c]) << 16);
        }
        return;
    }
    int blk = blockIdx.x - 2;
    hist[t] = 0; lcur[t] = 0;
    __syncthreads();

    int e0 = blk * CHUNK;
    int nv = min(CHUNK, E - e0);
    int dv[CHUNK / 256]; int sv[CHUNK / 256]; unsigned wv[CHUNK / 256];
#pragma unroll
    for (int j = 0; j < CHUNK / 256; ++j) {
        int idx = t + j * 256;
        if (idx < nv) {
            int e = e0 + idx;
            dv[j] = dst[e]; sv[j] = src[e]; wv[j] = __float_as_uint(ew[e]);
            atomicAdd(&hist[dv[j] >> BSHIFT], 1);
        } else dv[j] = -1;
    }
    __syncthreads();
    int hv = hist[t];
    sc[t] = hv;
    __syncthreads();
#pragma unroll
    for (int off = 1; off < 256; off <<= 1) {
        int a = (t >= off) ? sc[t - off] : 0;
        __syncthreads();
        sc[t] += a;
        __syncthreads();
    }
    exc[t] = sc[t] - hv;
    // reserve this block's run in bucket t (global, ~196 hot counters)
    basel[t] = (hv > 0) ? atomicAdd(&bucketCur[t], hv) : 0;
    __syncthreads();
#pragma unroll
    for (int j = 0; j < CHUNK / 256; ++j) {
        if (dv[j] >= 0) {
            int b  = dv[j] >> BSHIFT;
            int dl = dv[j] & (BNODES - 1);
            int p  = exc[b] + atomicAdd(&lcur[b], 1);
            ent[p] = make_uint2(((unsigned)dl << 17) | (unsigned)sv[j], wv[j]);
            bof[p] = (unsigned short)b;
        }
    }
    __syncthreads();
#pragma unroll
    for (int j = 0; j < CHUNK / 256; ++j) {
        int i = t + j * 256;
        if (i < nv) {
            int b = bof[i];
            csrTmp[(size_t)b * CAP + basel[b] + (i - exc[b])] = ent[i];
        }
    }
}

// ---- 2. bucketB: dinv, nodeinfo, node-sorted csrF={s,ew} ------------------

__global__ __launch_bounds__(1024) void bucketB_kernel(
    const uint2* __restrict__ csrTmp, const int* __restrict__ bucketSize,
    float* __restrict__ dinv, uint2* __restrict__ nodeinfo,
    uint2* __restrict__ csrF, int N)
{
    __shared__ uint2 ent[CAP];
    __shared__ unsigned long long dc[BNODES];
    __shared__ int scn[BNODES], beg[BNODES], cur[BNODES];
    int b = blockIdx.x, t = threadIdx.x;
    if (t < BNODES) { dc[t] = 0ull; cur[t] = 0; }
    __syncthreads();

    int sz = min(bucketSize[b], CAP);
    const uint2* reg = csrTmp + (size_t)b * CAP;
    for (int i = t; i < sz; i += 1024) {
        uint2 en = reg[i];
        ent[i] = en;
        int dl = (int)(en.x >> 17);
        unsigned fx = (unsigned)__float2uint_rn(__uint_as_float(en.y) * 16777216.0f);
        atomicAdd(&dc[dl], (1ull << 32) | (unsigned long long)fx);
    }
    __syncthreads();

    int cnt = 0; float dv = 1.0f;
    if (t < BNODES) {
        unsigned long long v = dc[t];
        cnt = (int)(v >> 32);
        dv = rsqrtf((float)(unsigned)(v & 0xffffffffull) * (1.0f / 16777216.0f) + 1.0f);
        scn[t] = cnt;
    }
    __syncthreads();
#pragma unroll
    for (int off = 1; off < BNODES; off <<= 1) {
        int a = 0;
        if (t < BNODES && t >= off) a = scn[t - off];
        __syncthreads();
        if (t < BNODES) scn[t] += a;
        __syncthreads();
    }
    if (t < BNODES) {
        int excl = scn[t] - cnt;
        beg[t] = excl;
        int gn = b * BNODES + t;
        if (gn < N) {
            dinv[gn] = dv;
            nodeinfo[gn] = make_uint2((unsigned)(b * CAP + excl), (unsigned)cnt);
        }
    }
    __syncthreads();

    uint2* outreg = csrF + (size_t)b * CAP;
    for (int i = t; i < sz; i += 1024) {
        uint2 en = ent[i];
        int dl = (int)(en.x >> 17);
        int p  = beg[dl] + atomicAdd(&cur[dl], 1);
        outreg[p] = make_uint2(en.x & 0x1FFFFu, en.y);   // {src, ew}
    }
}

// ---- 3. gemm1: h1s = dinv * (x @ W1), bf16-packed -------------------------

__global__ __launch_bounds__(256) void gemm1_kernel(
    const float* __restrict__ Xf, const unsigned* __restrict__ Wt,
    const float* __restrict__ dinv, unsigned* __restrict__ Hb, int M)
{
    constexpr int LW = 68, KU = 64;
    __shared__ unsigned sA[64 * LW];
    __shared__ unsigned sB[128 * LW];
    __shared__ float sD[64];
    const int t = threadIdx.x;
    const int rbase = blockIdx.x * 64;

    if (t < 64) sD[t] = (rbase + t < M) ? dinv[rbase + t] : 0.f;
    for (int f = t; f < 128 * 16; f += 256) {       // B: 128 rows x 16 uint4
        int c = f >> 4, qd = f & 15;
        *(uint4*)&sB[c * LW + qd * 4] = *(const uint4*)&Wt[c * KU + qd * 4];
    }
    for (int f = t; f < 64 * 32; f += 256) {        // A: fp32 -> bf16 pack
        int r = f >> 5, c4 = f & 31;
        int gr = rbase + r;
        float4 v = make_float4(0.f, 0.f, 0.f, 0.f);
        if (gr < M) v = *(const float4*)&Xf[(size_t)gr * 128 + c4 * 4];
        sA[r * LW + c4 * 2]     = bf16r(v.x) | (bf16r(v.y) << 16);
        sA[r * LW + c4 * 2 + 1] = bf16r(v.z) | (bf16r(v.w) << 16);
    }
    __syncthreads();

    const int wave = t >> 6, lane = t & 63;
    const int quad = lane >> 4, lr = lane & 15;
    const int n0 = wave * 32;

    f32x4 acc[4][2];
#pragma unroll
    for (int mi = 0; mi < 4; ++mi)
#pragma unroll
        for (int ni = 0; ni < 2; ++ni)
            acc[mi][ni] = (f32x4){0.f, 0.f, 0.f, 0.f};

#pragma unroll
    for (int ks = 0; ks < 4; ++ks) {
        int ko = ks * 16 + quad * 4;
        bf16x8 b0 = *(const bf16x8*)&sB[(n0 + lr) * LW + ko];
        bf16x8 b1 = *(const bf16x8*)&sB[(n0 + 16 + lr) * LW + ko];
#pragma unroll
        for (int mi = 0; mi < 4; ++mi) {
            bf16x8 a = *(const bf16x8*)&sA[(mi * 16 + lr) * LW + ko];
            acc[mi][0] = __builtin_amdgcn_mfma_f32_16x16x32_bf16(a, b0, acc[mi][0], 0, 0, 0);
            acc[mi][1] = __builtin_amdgcn_mfma_f32_16x16x32_bf16(a, b1, acc[mi][1], 0, 0, 0);
        }
    }
    __syncthreads();

    unsigned short* sO = (unsigned short*)sA;       // [64][2*LW]
#pragma unroll
    for (int mi = 0; mi < 4; ++mi)
#pragma unroll
        for (int ni = 0; ni < 2; ++ni)
#pragma unroll
            for (int r = 0; r < 4; ++r) {
                int row = mi * 16 + quad * 4 + r;
                sO[row * (2 * LW) + n0 + ni * 16 + lr] =
                    (unsigned short)bf16r(acc[mi][ni][r] * sD[row]);
            }
    __syncthreads();

    for (int f = t; f < 64 * 64; f += 256) {
        int row = f >> 6, cu = f & 63;
        int gr = rbase + row;
        if (gr < M) Hb[(size_t)gr * 64 + cu] = sA[row * LW + cu];
    }
}

// ---- 4. gg: gather h1s (+scale+bias+relu) + MFMA gemm2, h2s row-scaled ----
// 512 thr / 8 waves, 16 nodes.  Each wave: TWO nodes interleaved with a
// depth-1 software-pipelined row prefetch (best measured form).

__global__ __launch_bounds__(512, 4) void gg_kernel(
    const uint2* __restrict__ nodeinfo, const uint2* __restrict__ csr,
    const uint4* __restrict__ Hb4,                 // h1s row = 16 uint4
    const float* __restrict__ dinv, const float* __restrict__ bias,
    const unsigned* __restrict__ Wt2, unsigned* __restrict__ H2, int N)
{
    __shared__ __align__(16) unsigned sG[16 * 68];   // g1 tile bf16-packed
    __shared__ __align__(16) float    sO[16 * 68];   // h2 fp32 tile
    __shared__ float sDi[16];

    const int t = threadIdx.x, wave = t >> 6, lane = t & 63;
    const int q = lane >> 4, cg = lane & 15;
    const int nb = blockIdx.x * 16;
    if (t < 16) sDi[t] = dinv[nb + t];

    const int m0 = wave * 2, m1 = m0 + 1;
    const int n0 = nb + m0, n1 = nb + m1;    // 6250*16 == 100000: no tail

    float one0 = (q == 0) ? 1.f : 0.f;       // self-loop weight 1 (hs has dinv)
    float acc0[8], acc1[8];
    {
        uint4 su = Hb4[(size_t)n0 * 16 + cg];
        uint4 sv = Hb4[(size_t)n1 * 16 + cg];
        acc0[0] = bf_lo(su.x) * one0; acc0[1] = bf_hi(su.x) * one0;
        acc0[2] = bf_lo(su.y) * one0; acc0[3] = bf_hi(su.y) * one0;
        acc0[4] = bf_lo(su.z) * one0; acc0[5] = bf_hi(su.z) * one0;
        acc0[6] = bf_lo(su.w) * one0; acc0[7] = bf_hi(su.w) * one0;
        acc1[0] = bf_lo(sv.x) * one0; acc1[1] = bf_hi(sv.x) * one0;
        acc1[2] = bf_lo(sv.y) * one0; acc1[3] = bf_hi(sv.y) * one0;
        acc1[4] = bf_lo(sv.z) * one0; acc1[5] = bf_hi(sv.z) * one0;
        acc1[6] = bf_lo(sv.w) * one0; acc1[7] = bf_hi(sv.w) * one0;
    }
    uint2 i0 = nodeinfo[n0], i1 = nodeinfo[n1];
    int j0 = (int)i0.x, e0v = j0 + (int)i0.y;
    int j1 = (int)i1.x, e1v = j1 + (int)i1.y;

    while (j0 < e0v || j1 < e1v) {
        int cs0 = 0, cs1 = 0; float cw0 = 0.f, cw1 = 0.f;
        if (j0 + lane < e0v) { uint2 p = csr[j0 + lane]; cs0 = (int)p.x; cw0 = __uint_as_float(p.y); }
        if (j1 + lane < e1v) { uint2 p = csr[j1 + lane]; cs1 = (int)p.x; cw1 = __uint_as_float(p.y); }
        int r0 = e0v - j0; int mm0 = r0 < 0 ? 0 : (r0 > 64 ? 64 : r0);
        int r1 = e1v - j1; int mm1 = r1 < 0 ? 0 : (r1 > 64 ? 64 : r1);
        int mmx = mm0 > mm1 ? mm0 : mm1;

        // prologue: slot q of both nodes (cs/cw are 0 beyond each node's mm,
        // so the short node degenerates to cached row-0 loads with w=0)
        int   s0 = __shfl(cs0, q),  s1 = __shfl(cs1, q);
        float w0 = __shfl(cw0, q),  w1 = __shfl(cw1, q);
        uint4 u0 = Hb4[(size_t)s0 * 16 + cg];
        uint4 u1 = Hb4[(size_t)s1 * 16 + cg];

        for (int k = 0; k < mmx; k += 4) {
            uint4 u0n = u0, u1n = u1;
            float w0n = 0.f, w1n = 0.f;
            if (k + 4 < mmx) {                     // wave-uniform
                int s0n = __shfl(cs0, k + 4 + q), s1n = __shfl(cs1, k + 4 + q);
                w0n = __shfl(cw0, k + 4 + q);     w1n = __shfl(cw1, k + 4 + q);
                u0n = Hb4[(size_t)s0n * 16 + cg];
                u1n = Hb4[(size_t)s1n * 16 + cg];
            }
            fma8(acc0, u0, w0);
            fma8(acc1, u1, w1);
            u0 = u0n; u1 = u1n; w0 = w0n; w1 = w1n;
        }
        j0 += 64; j1 += 64;
    }

#pragma unroll
    for (int v = 0; v < 8; ++v) {
        acc0[v] += __shfl_xor(acc0[v], 16);
        acc0[v] += __shfl_xor(acc0[v], 32);
        acc1[v] += __shfl_xor(acc1[v], 16);
        acc1[v] += __shfl_xor(acc1[v], 32);
    }
    if (q == 0) {
        int c = cg * 8;
        float di0 = dinv[n0];
        uint4 pk;
        pk.x = bf16r(fmaxf(acc0[0] * di0 + bias[c + 0], 0.f)) |
               (bf16r(fmaxf(acc0[1] * di0 + bias[c + 1], 0.f)) << 16);
        pk.y = bf16r(fmaxf(acc0[2] * di0 + bias[c + 2], 0.f)) |
               (bf16r(fmaxf(acc0[3] * di0 + bias[c + 3], 0.f)) << 16);
        pk.z = bf16r(fmaxf(acc0[4] * di0 + bias[c + 4], 0.f)) |
               (bf16r(fmaxf(acc0[5] * di0 + bias[c + 5], 0.f)) << 16);
        pk.w = bf16r(fmaxf(acc0[6] * di0 + bias[c + 6], 0.f)) |
               (bf16r(fmaxf(acc0[7] * di0 + bias[c + 7], 0.f)) << 16);
        *(uint4*)&sG[m0 * 68 + cg * 4] = pk;
        float di1 = dinv[n1];
        pk.x = bf16r(fmaxf(acc1[0] * di1 + bias[c + 0], 0.f)) |
               (bf16r(fmaxf(acc1[1] * di1 + bias[c + 1], 0.f)) << 16);
        pk.y = bf16r(fmaxf(acc1[2] * di1 + bias[c + 2], 0.f)) |
               (bf16r(fmaxf(acc1[3] * di1 + bias[c + 3], 0.f)) << 16);
        pk.z = bf16r(fmaxf(acc1[4] * di1 + bias[c + 4], 0.f)) |
               (bf16r(fmaxf(acc1[5] * di1 + bias[c + 5], 0.f)) << 16);
        pk.w = bf16r(fmaxf(acc1[6] * di1 + bias[c + 6], 0.f)) |
               (bf16r(fmaxf(acc1[7] * di1 + bias[c + 7], 0.f)) << 16);
        *(uint4*)&sG[m1 * 68 + cg * 4] = pk;
    }
    __syncthreads();

    // h2 tile: waves 0..3 each compute n-tile n0 = wave*16
    if (wave < 4) {
        const int quad = lane >> 4, lr = lane & 15;
        const int nt0 = wave * 16;
        f32x4 accv = (f32x4){0.f, 0.f, 0.f, 0.f};
#pragma unroll
        for (int ks = 0; ks < 4; ++ks) {
            int ko = ks * 16 + quad * 4;
            bf16x8 av = *(const bf16x8*)&sG[lr * 68 + ko];
            bf16x8 bv = *(const bf16x8*)&Wt2[(nt0 + lr) * 64 + ko];
            accv = __builtin_amdgcn_mfma_f32_16x16x32_bf16(av, bv, accv, 0, 0, 0);
        }
#pragma unroll
        for (int r = 0; r < 4; ++r)
            sO[(quad * 4 + r) * 68 + nt0 + lr] = accv[r];
    }
    __syncthreads();

    if (t < 512) {                         // 16 rows x 32 packed uints
        int row = t >> 5, cu = t & 31;
        float sc = sDi[row];               // h2s = dinv * h2
        unsigned pk = bf16r(sO[row * 68 + 2 * cu] * sc) |
                      (bf16r(sO[row * 68 + 2 * cu + 1] * sc) << 16);
        H2[(size_t)(nb + row) * 32 + cu] = pk;
    }
}

// ---- 5. gather64: aggregate h2s -> out fp32 -------------------------------
// 256 thr / 4 waves, 8 nodes per block (2 per wave, pipelined).

__global__ __launch_bounds__(256, 4) void gather64_kernel(
    const uint2* __restrict__ nodeinfo, const uint2* __restrict__ csr,
    const uint4* __restrict__ Hb4,                 // h2s row = 8 uint4
    const float* __restrict__ dinv, const float* __restrict__ bias,
    float* __restrict__ OUT, int N)
{
    const int wave = threadIdx.x >> 6, lane = threadIdx.x & 63;
    const int n0 = blockIdx.x * 8 + wave * 2, n1 = n0 + 1;
    if (n0 >= N) return;                   // N even: n1 valid whenever n0 is
    const int q  = lane >> 3;              // slot 0..7
    const int cg = lane & 7;

    float one0 = (q == 0) ? 1.f : 0.f;
    float acc0[8], acc1[8];
    {
        uint4 su = Hb4[(size_t)n0 * 8 + cg];
        uint4 sv = Hb4[(size_t)n1 * 8 + cg];
        acc0[0] = bf_lo(su.x) * one0; acc0[1] = bf_hi(su.x) * one0;
        acc0[2] = bf_lo(su.y) * one0; acc0[3] = bf_hi(su.y) * one0;
        acc0[4] = bf_lo(su.z) * one0; acc0[5] = bf_hi(su.z) * one0;
        acc0[6] = bf_lo(su.w) * one0; acc0[7] = bf_hi(su.w) * one0;
        acc1[0] = bf_lo(sv.x) * one0; acc1[1] = bf_hi(sv.x) * one0;
        acc1[2] = bf_lo(sv.y) * one0; acc1[3] = bf_hi(sv.y) * one0;
        acc1[4] = bf_lo(sv.z) * one0; acc1[5] = bf_hi(sv.z) * one0;
        acc1[6] = bf_lo(sv.w) * one0; acc1[7] = bf_hi(sv.w) * one0;
    }

    uint2 i0 = nodeinfo[n0], i1 = nodeinfo[n1];
    int j0 = (int)i0.x, e0v = j0 + (int)i0.y;
    int j1 = (int)i1.x, e1v = j1 + (int)i1.y;

    while (j0 < e0v || j1 < e1v) {
        int cs0 = 0, cs1 = 0; float cw0 = 0.f, cw1 = 0.f;
        if (j0 + lane < e0v) { uint2 p = csr[j0 + lane]; cs0 = (int)p.x; cw0 = __uint_as_float(p.y); }
        if (j1 + lane < e1v) { uint2 p = csr[j1 + lane]; cs1 = (int)p.x; cw1 = __uint_as_float(p.y); }
        int r0 = e0v - j0; int mm0 = r0 < 0 ? 0 : (r0 > 64 ? 64 : r0);
        int r1 = e1v - j1; int mm1 = r1 < 0 ? 0 : (r1 > 64 ? 64 : r1);
        int mmx = mm0 > mm1 ? mm0 : mm1;

        int   s0 = __shfl(cs0, q),  s1 = __shfl(cs1, q);
        float w0 = __shfl(cw0, q),  w1 = __shfl(cw1, q);
        uint4 u0 = Hb4[(size_t)s0 * 8 + cg];
        uint4 u1 = Hb4[(size_t)s1 * 8 + cg];

        for (int k = 0; k < mmx; k += 8) {
            uint4 u0n = u0, u1n = u1;
            float w0n = 0.f, w1n = 0.f;
            if (k + 8 < mmx) {                     // wave-uniform
                int s0n = __shfl(cs0, k + 8 + q), s1n = __shfl(cs1, k + 8 + q);
                w0n = __shfl(cw0, k + 8 + q);     w1n = __shfl(cw1, k + 8 + q);
                u0n = Hb4[(size_t)s0n * 8 + cg];
                u1n = Hb4[(size_t)s1n * 8 + cg];
            }
            fma8(acc0, u0, w0);
            fma8(acc1, u1, w1);
            u0 = u0n; u1 = u1n; w0 = w0n; w1 = w1n;
        }
        j0 += 64; j1 += 64;
    }

#pragma unroll
    for (int v = 0; v < 8; ++v) {
        acc0[v] += __shfl_xor(acc0[v], 8);
        acc0[v] += __shfl_xor(acc0[v], 16);
        acc0[v] += __shfl_xor(acc0[v], 32);
        acc1[v] += __shfl_xor(acc1[v], 8);
        acc1[v] += __shfl_xor(acc1[v], 16);
        acc1[v] += __shfl_xor(acc1[v], 32);
    }

    int c = cg * 8 + q;
    OUT[(size_t)n0 * 64 + c] = acc0[q] * dinv[n0] + bias[c];
    OUT[(size_t)n1 * 64 + c] = acc1[q] * dinv[n1] + bias[c];
}

static inline size_t align_up(size_t x) { return (x + 255) & ~size_t(255); }

extern "C" void kernel_launch(void* const* d_in, const int* in_sizes, int n_in,
                              void* d_out, int out_size, void* d_ws, size_t ws_size,
                              hipStream_t stream)
{
    const float* x  = (const float*)d_in[0];
    const int*   ei = (const int*)d_in[1];
    const float* ew = (const float*)d_in[2];
    const float* W1 = (const float*)d_in[3];
    const float* b1 = (const float*)d_in[4];
    const float* W2 = (const float*)d_in[5];
    const float* b2 = (const float*)d_in[6];
    float* out = (float*)d_out;

    const int N = N_NODES;
    const int E = in_sizes[2];
    const int* src = ei;
    const int* dst = ei + E;

    const int NBLK = (E + CHUNK - 1) / CHUNK;
    const size_t REGION = (size_t)NBUCK * CAP;

    char* ws = (char*)d_ws;
    int*   bucketCur = (int*)ws;   ws += align_up((size_t)NBUCK * 4);
    float* dinv      = (float*)ws; ws += align_up((size_t)N * 4);
    uint2* nodeinfo  = (uint2*)ws; ws += align_up((size_t)N * 8);
    uint2* csrTmp    = (uint2*)ws; ws += align_up(REGION * 8);
    uint2* csrF      = (uint2*)ws; ws += align_up(REGION * 8);
    unsigned* Wt1    = (unsigned*)ws; ws += align_up((size_t)128 * 64 * 4);
    unsigned* Wt2    = (unsigned*)ws; ws += align_up((size_t)64 * 64 * 4);
    unsigned* h1     = (unsigned*)ws; ws += align_up((size_t)N * 64 * 4);  // h1s bf16 pk
    unsigned* h2     = (unsigned*)ws; ws += align_up((size_t)N * 32 * 4);  // h2s bf16 pk

    hipMemsetAsync(bucketCur, 0, (size_t)NBUCK * 4, stream);
    a2F_kernel<<<NBLK + 2, 256, 0, stream>>>(src, dst, ew, W1, W2,
                                             Wt1, Wt2, bucketCur, csrTmp, E);
    bucketB_kernel<<<NBUCK, 1024, 0, stream>>>(csrTmp, bucketCur, dinv, nodeinfo, csrF, N);
    gemm1_kernel<<<(N + 63) / 64, 256, 0, stream>>>(x, Wt1, dinv, h1, N);
    gg_kernel<<<N / 16, 512, 0, stream>>>(nodeinfo, csrF, (const uint4*)h1,
                                          dinv, b1, Wt2, h2, N);
    gather64_kernel<<<(N + 7) / 8, 256, 0, stream>>>(
        nodeinfo, csrF, (const uint4*)h2, dinv, b2, out, N);
}